// Round 5
// baseline (271.104 us; speedup 1.0000x reference)
//
#include <hip/hip_runtime.h>

typedef _Float16 f16;
typedef _Float16 f16x8 __attribute__((ext_vector_type(8)));
typedef _Float16 f16x4 __attribute__((ext_vector_type(4)));
typedef float v4f __attribute__((ext_vector_type(4)));

constexpr int H = 512, W = 512, NB = 8;
constexpr int ROWS = 514;               // padded rows
constexpr int COLS = 528;               // px p at col p+8
constexpr int CH = 8;
constexpr size_t ROWBYTES = (size_t)COLS * CH * 2;        // 8448
constexpr size_t PLANE_ELEMS = (size_t)ROWS * COLS * CH;
constexpr size_t PLANE_BYTES = PLANE_ELEMS * 2;

constexpr int WTAB_L = 3072;

// fused kernel (64px tiles): row = 80 px + 1 pad = 81 px * 16B = 1296 B
constexpr int FRSP = 81;
constexpr int FRSPC = FRSP * CH;        // 648 f16
constexpr int FROWB = FRSP * 16;        // 1296 B
constexpr int INR = 20;                 // input ring rows (2-strip-deep staging)
constexpr int ARR = 10;                 // A-ring rows

__device__ __forceinline__ void gload_lds16(const void* g, void* l) {
    __builtin_amdgcn_global_load_lds(
        (const __attribute__((address_space(1))) unsigned int*)g,
        (__attribute__((address_space(3))) unsigned int*)l, 16, 0, 0);
}

// ---------------- init: zero borders of 2 plane-sets + build wtab -------------
// grid (42, g, 2) x 256. bx<37: border zeroing (i = bx*256+tid over 9248).
// bx 37..41 (y==0,z==0 copy only): weight fragments, 4 layers per block.
// wtab slots: 0..17 = conv2..19 (8->8), 18 = conv20 (8->1), 19 = conv1 (1->8,
// input channels 0/1 carry the hi/lo f16 split of the f32 input).
__global__ void init_kernel(const float* __restrict__ w1,
                            const float* __restrict__ wmid,
                            const float* __restrict__ w20,
                            f16* __restrict__ wtab,
                            f16* __restrict__ base, size_t set_stride) {
    const int bx = blockIdx.x;
    if (bx < 37) {
        const int i = bx * 256 + threadIdx.x;
        if (i >= 9248) return;
        const int img = blockIdx.y, set = blockIdx.z;
        int row, col;
        if (i < 1056) { row = (i < 528) ? 0 : 513; col = (i < 528) ? i : i - 528; }
        else {
            const int j = i - 1056;
            row = 1 + (j >> 4);
            const int c4 = j & 15;
            col = (c4 < 8) ? c4 : 512 + c4;
        }
        f16x8 z = {};
        f16* p = base + (size_t)set * set_stride + ((size_t)img * ROWS + row) * COLS * CH + (size_t)col * CH;
        *(f16x8*)p = z;
        return;
    }
    if (blockIdx.y != 0 || blockIdx.z != 0) return;
    const int l = (bx - 37) * 4 + (threadIdx.x >> 6);
    if (l >= 20) return;
    const int lane = threadIdx.x & 63;
    const float* wt = (l < 18) ? wmid + (size_t)l * 576 : (l == 18 ? w20 : w1);
    const int COUT = (l == 18) ? 1 : 8;
    const bool c1 = (l == 19);
    const int n = lane & 15, q = lane >> 4;
#pragma unroll
    for (int g = 0; g < 3; ++g) {
        const int t = g * 4 + q;
        f16x8 hv, lv;
#pragma unroll
        for (int j = 0; j < 8; ++j) {
            float wv = 0.f;
            if (c1) {
                if (n < 8) { if (t <= 8 && j < 2) wv = wt[n * 9 + t]; }
                else       { const int o = n - 8; if (t >= 3 && j < 2) wv = wt[o * 9 + (t - 3)]; }
            } else if (n < 8) {
                if (t <= 8 && n < COUT) wv = wt[(n * 8 + j) * 9 + t];
            } else {
                const int o = n - 8;
                if (t >= 3 && o < COUT) wv = wt[(o * 8 + j) * 9 + (t - 3)];
            }
            const f16 h = (f16)wv;
            hv[j] = h;
            lv[j] = (f16)(wv - (float)h);
        }
        f16* dst = wtab + (size_t)l * WTAB_L + (g * 2) * 512 + lane * 8;
        *(f16x8*)dst = hv;
        *(f16x8*)(dst + 512) = lv;
    }
}

// ---------------- FUSED 2-layer conv, r8 schedule at 4 blocks/CU --------------
// MODE 0: mid pair (f16 plane in, f16 plane out)
// MODE 1: first pair (conv1+conv2): f32 single-ch input, reg-staged into the
//         ring as hi/lo f16 in ch0/1 (ch2-7 zero); A uses wtab slot 19.
// MODE 2: last pair (conv19+conv20): B stores f32 ch0 to output, no relu.
// Block 256 = 4 waves; grid (img, 8 x-tiles, 16 chunks) = 1024 -> 4 blocks/CU
// (grid provides exactly 4/CU; 5th occupancy slot has no work, so LDS budget
// is 40 KB and we use 38.9 KB).
// COUNTED-BARRIER PIPELINE (this round): staging issues 2 strips ahead
// (INR=20), and the in-loop barriers are raw s_barrier with counted waits:
//   bar1 (A visible):    s_waitcnt lgkmcnt(0)           -- DMA stays in flight
//   bar2 (strip commit): s_waitcnt vmcnt(8) lgkmcnt(0)  -- lets this strip's
//     {4 stage-DMA + 4 stores} stay outstanding; everything older (the
//     previous strip's staging = rows the next computeA reads) has retired
//     (vmcnt retires oldest-first).
// Slot liveness (mod 20): stage(strip t) writes rows +8t+19..+26 == slots of
// rows +8t-1..+6, whose last reader is computeA of strip t (ph1), and the
// write is issued in ph2 after bar1 -> barrier-separated. aring unchanged
// (ARR=10, A(t+1) overwrite of B(t)-read slots separated by bar2).
// s_setprio 1 inside compute lambdas (measured -10 us, round 3). 3-layer
// fusion parked: weight regs blow the 128/wave budget (rounds 1-2).
template<int MODE>
__global__ __launch_bounds__(256, 4) void conv2fused(
    const f16* __restrict__ in,
    const f16* __restrict__ wtA, const f16* __restrict__ wtB,
    f16* __restrict__ outp, float* __restrict__ outf)
{
    // aring FIRST: A-phase halo reads at inring col -1 (feeding only the
    // unused A output col 0) land in aring's tail, inside the shared block.
    __shared__ __align__(16) f16 aring[ARR * FRSPC];   // 12960 B
    __shared__ __align__(16) f16 inring[INR * FRSPC];  // 25920 B

    const int wave = threadIdx.x >> 6, lane = threadIdx.x & 63;
    const int img = blockIdx.x, xt = blockIdx.y;
    const int x0 = xt * 64;
    const int base = blockIdx.z * 32;   // B outputs padded rows base+1..base+32

    f16x8 ahiW[3], aloW[3], bhiW[3], bloW[3];
#pragma unroll
    for (int g = 0; g < 3; ++g) {
        const f16* wa = wtA + (g * 2) * 512 + lane * 8;
        ahiW[g] = *(const f16x8*)wa;  aloW[g] = *(const f16x8*)(wa + 512);
        const f16* wb = wtB + (g * 2) * 512 + lane * 8;
        bhiW[g] = *(const f16x8*)wb;  bloW[g] = *(const f16x8*)(wb + 512);
    }

    // global src at px x0-8 (padded col x0); rows are 80px = 1280 B
    const char* src = (const char*)in + (size_t)img * PLANE_BYTES + (size_t)x0 * 16;

    // stage padded rows [r0, r0+cnt), slot = row mod 20
    auto stage = [&](int r0, int cnt) {
        for (int rr = wave; rr < cnt; rr += 4) {
            const int row = r0 + rr;
            const int slot = ((row % INR) + INR) % INR;
            if constexpr (MODE == 1) {
                // f32 input, single channel -> hi/lo f16 in ch0/1, rest zero
                const float* xin = (const float*)in;
                const int iy = row - 1;                      // padded -> image row
                const bool vr = (iy >= 0) && (iy < H);
                const float* xr = xin + (size_t)img * H * W + (size_t)(vr ? iy : 0) * W;
                f16* ld = inring + slot * FRSPC;
#pragma unroll
                for (int k = 0; k < 2; ++k) {
                    if (k == 1 && lane >= 16) continue;
                    const int ci = 64 * k + lane;            // ring col 0..79
                    const int px = x0 - 8 + ci;
                    const float v = (vr && px >= 0 && px < W) ? xr[px] : 0.f;
                    const f16 h = (f16)v;
                    f16x8 o = {};
                    o[0] = h; o[1] = (f16)(v - (float)h);
                    *(f16x8*)&ld[(size_t)ci * CH] = o;
                }
            } else {
                const int rowc = min(max(row, 0), 513);
                const char* gs = src + (size_t)rowc * ROWBYTES;
                char* ld = (char*)inring + slot * FROWB;
                gload_lds16(gs + lane * 16, ld);                                // 1024 B
                if (lane < 16) gload_lds16(gs + 1024 + lane * 16, ld + 1024);   // 256 B
            }
        }
    };

    const int n = lane & 15, q = lane >> 4;
    int tyv[3], txv[3];
#pragma unroll
    for (int g = 0; g < 3; ++g) { const int t = g * 4 + q; tyv[g] = t / 3 - 1; txv[g] = t % 3 - 1; }
    const int rowoff = q >> 1, choff = (q & 1) * 4;
    const bool xe0 = (xt == 0), xe7 = (xt == 7);

    // A-phase: rows (rA, rA+1); A cols c=16s+n (s=0..4), px = x0-8+c -> aring
    auto computeA = [&](int rA) {
        __builtin_amdgcn_s_setprio(1);
        int irow[3];
#pragma unroll
        for (int g = 0; g < 3; ++g) {
            const int r = rA + tyv[g];
            irow[g] = (((r % INR) + INR) % INR) * FRSPC;
        }
        const int gyA = rA + rowoff;
        const int wrow = (gyA % ARR) * FRSPC;
        const bool zr = (gyA == 0) || (gyA == 513);
#pragma unroll
        for (int s = 0; s < 5; ++s) {
            v4f acc = {0.f,0.f,0.f,0.f}, acc2 = {0.f,0.f,0.f,0.f};
#pragma unroll
            for (int g = 0; g < 3; ++g) {
                const f16x8 xv = *(const f16x8*)&inring[irow[g] + (16 * s + n + txv[g]) * CH];
                acc  = __builtin_amdgcn_mfma_f32_16x16x32_f16(ahiW[g], xv, acc,  0, 0, 0);
                acc2 = __builtin_amdgcn_mfma_f32_16x16x32_f16(aloW[g], xv, acc2, 0, 0, 0);
            }
            const v4f res = acc + acc2;
            f16x4 hv;
#pragma unroll
            for (int c = 0; c < 4; ++c) hv[c] = (f16)fmaxf(res[c], 0.f);
            // SAME-pad for B: zero at global borders (rows 0/513; px -1 at
            // xt==0 -> col 7 (s0,n7); px 512 at xt==7 -> col 72 (s4,n8))
            if (zr || (xe0 && s == 0 && n == 7) || (xe7 && s == 4 && n == 8)) {
                hv[0] = (f16)0.f; hv[1] = (f16)0.f; hv[2] = (f16)0.f; hv[3] = (f16)0.f;
            }
            *(f16x4*)&aring[wrow + (16 * s + n) * CH + choff] = hv;
        }
        __builtin_amdgcn_s_setprio(0);
    };

    // B-phase: rows (rB, rB+1); B px = x0+16s+n (s=0..3)
    auto computeB = [&](int rB) {
        __builtin_amdgcn_s_setprio(1);
        int brow[3];
#pragma unroll
        for (int g = 0; g < 3; ++g) brow[g] = ((rB + tyv[g]) % ARR) * FRSPC;
        const int gyB = rB + rowoff;
        f16* orow = outp + ((size_t)img * ROWS + gyB) * COLS * CH + (size_t)(x0 + 8) * CH + choff;
#pragma unroll
        for (int s = 0; s < 4; ++s) {
            v4f acc = {0.f,0.f,0.f,0.f}, acc2 = {0.f,0.f,0.f,0.f};
#pragma unroll
            for (int g = 0; g < 3; ++g) {
                const f16x8 xv = *(const f16x8*)&aring[brow[g] + (16 * s + n + txv[g] + 8) * CH];
                acc  = __builtin_amdgcn_mfma_f32_16x16x32_f16(bhiW[g], xv, acc,  0, 0, 0);
                acc2 = __builtin_amdgcn_mfma_f32_16x16x32_f16(bloW[g], xv, acc2, 0, 0, 0);
            }
            const v4f res = acc + acc2;
            if constexpr (MODE == 2) {
                // conv20: 8->1, no relu, f32 store (ch0 lives in choff==0 lanes)
                if (choff == 0)
                    outf[((size_t)img * H + (gyB - 1)) * W + (x0 + 16 * s + n)] = res[0];
            } else {
                f16x4 hv;
#pragma unroll
                for (int c = 0; c < 4; ++c) hv[c] = (f16)fmaxf(res[c], 0.f);
                *(f16x4*)(orow + (size_t)(16 * s + n) * CH) = hv;
            }
        }
        __builtin_amdgcn_s_setprio(0);
    };

    // ---- prime: input rows base-1..base+18 (20); A pair (base, base+1) ----
    stage(base - 1, 20);
    __syncthreads();
    if (wave == 0) computeA(base);

    for (int t = 0; t < 4; ++t) {
        computeA(base + 8 * t + 2 + 2 * wave);       // A rows [b+8t+2 .. +9]
        // bar1: aring visible; DMA (2 strips deep) stays in flight
        asm volatile("s_waitcnt lgkmcnt(0)" ::: "memory");
        __builtin_amdgcn_s_barrier();
        __builtin_amdgcn_sched_barrier(0);
        if (t < 2) stage(base + 8 * t + 19, 8);      // rows +19..+26 (for A t+2)
        computeB(base + 8 * t + 1 + 2 * wave);       // B rows [b+8t+1 .. +8]
        // bar2: counted drain -- this strip's 8 vm ops (4 stage + 4 stores)
        // may stay outstanding; older staging (needed by A of t+1) retired.
        asm volatile("s_waitcnt vmcnt(8) lgkmcnt(0)" ::: "memory");
        __builtin_amdgcn_s_barrier();
        __builtin_amdgcn_sched_barrier(0);
    }
}

extern "C" void kernel_launch(void* const* d_in, const int* in_sizes, int n_in,
                              void* d_out, int out_size, void* d_ws, size_t ws_size,
                              hipStream_t stream) {
    const float* x    = (const float*)d_in[0];
    const float* w1   = (const float*)d_in[1];
    const float* wmid = (const float*)d_in[2];
    const float* w20  = (const float*)d_in[3];
    float* out = (float*)d_out;

    const size_t wtab_bytes = (size_t)20 * WTAB_L * 2;
    int g = NB;
    while (g > 1 && 2 * (size_t)g * PLANE_BYTES + wtab_bytes > ws_size) g >>= 1;

    f16* act0 = (f16*)d_ws;
    f16* act1 = act0 + (size_t)g * PLANE_ELEMS;
    f16* wtab = act1 + (size_t)g * PLANE_ELEMS;

    init_kernel<<<dim3(42, g, 2), 256, 0, stream>>>(
        w1, wmid, w20, wtab, act0, (size_t)g * PLANE_ELEMS);

    for (int b0 = 0; b0 < NB; b0 += g) {
        // layers 1+2: f32 input -> act0   (A = wtab slot 19 = conv1, B = slot 0)
        conv2fused<1><<<dim3(g, 8, 16), 256, 0, stream>>>(
            (const f16*)(x + (size_t)b0 * H * W),
            wtab + (size_t)19 * WTAB_L, wtab + (size_t)0 * WTAB_L,
            act0, nullptr);
        // layers (2k+1, 2k+2) for k=1..8: slots (2k-1, 2k); ping-pong planes
        for (int k = 1; k <= 8; ++k) {
            const f16* s0 = (k & 1) ? act0 : act1;
            f16*       d0 = (k & 1) ? act1 : act0;
            conv2fused<0><<<dim3(g, 8, 16), 256, 0, stream>>>(
                s0, wtab + (size_t)(2 * k - 1) * WTAB_L, wtab + (size_t)(2 * k) * WTAB_L,
                d0, nullptr);
        }
        // layers 19+20: act0 -> f32 out  (A = slot 17, B = slot 18 = conv20)
        conv2fused<2><<<dim3(g, 8, 16), 256, 0, stream>>>(
            act0, wtab + (size_t)17 * WTAB_L, wtab + (size_t)18 * WTAB_L,
            nullptr, out + (size_t)b0 * H * W);
    }
}

// Round 6
// 259.548 us; speedup vs baseline: 1.0445x; 1.0445x over previous
//
#include <hip/hip_runtime.h>

typedef _Float16 f16;
typedef _Float16 f16x8 __attribute__((ext_vector_type(8)));
typedef _Float16 f16x4 __attribute__((ext_vector_type(4)));
typedef float v4f __attribute__((ext_vector_type(4)));

constexpr int H = 512, W = 512, NB = 8;
constexpr int ROWS = 514;               // padded rows
constexpr int COLS = 528;               // px p at col p+8
constexpr int CH = 8;
constexpr size_t ROWBYTES = (size_t)COLS * CH * 2;        // 8448
constexpr size_t PLANE_ELEMS = (size_t)ROWS * COLS * CH;
constexpr size_t PLANE_BYTES = PLANE_ELEMS * 2;

constexpr int WTAB_L = 3072;

// fused kernel (64px tiles): row = 80 px + 1 pad = 81 px * 16B = 1296 B
constexpr int FRSP = 81;
constexpr int FRSPC = FRSP * CH;        // 648 f16
constexpr int FROWB = FRSP * 16;        // 1296 B
constexpr int INR = 12;                 // input ring rows (r8 schedule, minimal)
constexpr int ARR = 10;                 // A-ring rows

__device__ __forceinline__ void gload_lds16(const void* g, void* l) {
    __builtin_amdgcn_global_load_lds(
        (const __attribute__((address_space(1))) unsigned int*)g,
        (__attribute__((address_space(3))) unsigned int*)l, 16, 0, 0);
}

// ---------------- init: zero borders of 2 plane-sets + build wtab -------------
// grid (42, g, 2) x 256. bx<37: border zeroing (i = bx*256+tid over 9248).
// bx 37..41 (y==0,z==0 copy only): weight fragments, 4 layers per block.
// wtab slots: 0..17 = conv2..19 (8->8), 18 = conv20 (8->1), 19 = conv1 (1->8,
// input channels 0/1 carry the hi/lo f16 split of the f32 input).
__global__ void init_kernel(const float* __restrict__ w1,
                            const float* __restrict__ wmid,
                            const float* __restrict__ w20,
                            f16* __restrict__ wtab,
                            f16* __restrict__ base, size_t set_stride) {
    const int bx = blockIdx.x;
    if (bx < 37) {
        const int i = bx * 256 + threadIdx.x;
        if (i >= 9248) return;
        const int img = blockIdx.y, set = blockIdx.z;
        int row, col;
        if (i < 1056) { row = (i < 528) ? 0 : 513; col = (i < 528) ? i : i - 528; }
        else {
            const int j = i - 1056;
            row = 1 + (j >> 4);
            const int c4 = j & 15;
            col = (c4 < 8) ? c4 : 512 + c4;
        }
        f16x8 z = {};
        f16* p = base + (size_t)set * set_stride + ((size_t)img * ROWS + row) * COLS * CH + (size_t)col * CH;
        *(f16x8*)p = z;
        return;
    }
    if (blockIdx.y != 0 || blockIdx.z != 0) return;
    const int l = (bx - 37) * 4 + (threadIdx.x >> 6);
    if (l >= 20) return;
    const int lane = threadIdx.x & 63;
    const float* wt = (l < 18) ? wmid + (size_t)l * 576 : (l == 18 ? w20 : w1);
    const int COUT = (l == 18) ? 1 : 8;
    const bool c1 = (l == 19);
    const int n = lane & 15, q = lane >> 4;
#pragma unroll
    for (int g = 0; g < 3; ++g) {
        const int t = g * 4 + q;
        f16x8 hv, lv;
#pragma unroll
        for (int j = 0; j < 8; ++j) {
            float wv = 0.f;
            if (c1) {
                if (n < 8) { if (t <= 8 && j < 2) wv = wt[n * 9 + t]; }
                else       { const int o = n - 8; if (t >= 3 && j < 2) wv = wt[o * 9 + (t - 3)]; }
            } else if (n < 8) {
                if (t <= 8 && n < COUT) wv = wt[(n * 8 + j) * 9 + t];
            } else {
                const int o = n - 8;
                if (t >= 3 && o < COUT) wv = wt[(o * 8 + j) * 9 + (t - 3)];
            }
            const f16 h = (f16)wv;
            hv[j] = h;
            lv[j] = (f16)(wv - (float)h);
        }
        f16* dst = wtab + (size_t)l * WTAB_L + (g * 2) * 512 + lane * 8;
        *(f16x8*)dst = hv;
        *(f16x8*)(dst + 512) = lv;
    }
}

// ---------------- FUSED 2-layer conv, r8 schedule at 4 blocks/CU --------------
// MODE 0: mid pair (f16 plane in, f16 plane out)
// MODE 1: first pair (conv1+conv2): f32 single-ch input, reg-staged into the
//         ring as hi/lo f16 in ch0/1 (ch2-7 zero); A uses wtab slot 19.
// MODE 2: last pair (conv19+conv20): B stores f32 ch0 to output, no relu.
// Block 256 = 4 waves; grid (img, 8 x-tiles, 16 chunks) = 1024 -> 4 blocks/CU.
// Per strip t: computeA(t) -> barrier -> stage(t+1) + computeB(t) -> barrier.
// The barrier's vmcnt(0) drain is structural (__syncthreads drains DMA) and is
// hidden by TLP across 4 independent blocks -- round 5 re-proved that counted
// s_barrier/vmcnt + sched_barrier pipelining REGRESSES (260->271 us, m141-class
// order-pinning loss). Do not re-attempt source-level pipelining here.
// s_setprio 1 inside compute lambdas: +3.5% (round 3, T5 role-diversity).
// 3-layer fusion parked: weight regs blow the 128/wave budget (rounds 1-2).
// 128px tiles parked: ARR=10/INR=12 minimum (2-row MFMA pairs) -> 51KB LDS
// at 145px stride > 40KB budget for 4 blocks/CU.
template<int MODE>
__global__ __launch_bounds__(256, 4) void conv2fused(
    const f16* __restrict__ in,
    const f16* __restrict__ wtA, const f16* __restrict__ wtB,
    f16* __restrict__ outp, float* __restrict__ outf)
{
    // aring FIRST: A-phase halo reads at inring col -1 (feeding only the
    // unused A output col 0) land in aring's tail, inside the shared block.
    __shared__ __align__(16) f16 aring[ARR * FRSPC];   // 12960 B
    __shared__ __align__(16) f16 inring[INR * FRSPC];  // 15552 B

    const int wave = threadIdx.x >> 6, lane = threadIdx.x & 63;
    const int img = blockIdx.x, xt = blockIdx.y;
    const int x0 = xt * 64;
    const int base = blockIdx.z * 32;   // B outputs padded rows base+1..base+32

    f16x8 ahiW[3], aloW[3], bhiW[3], bloW[3];
#pragma unroll
    for (int g = 0; g < 3; ++g) {
        const f16* wa = wtA + (g * 2) * 512 + lane * 8;
        ahiW[g] = *(const f16x8*)wa;  aloW[g] = *(const f16x8*)(wa + 512);
        const f16* wb = wtB + (g * 2) * 512 + lane * 8;
        bhiW[g] = *(const f16x8*)wb;  bloW[g] = *(const f16x8*)(wb + 512);
    }

    // global src at px x0-8 (padded col x0); rows are 80px = 1280 B
    const char* src = (const char*)in + (size_t)img * PLANE_BYTES + (size_t)x0 * 16;

    // stage padded rows [r0, r0+cnt), slot = row mod 12
    auto stage = [&](int r0, int cnt) {
        for (int rr = wave; rr < cnt; rr += 4) {
            const int row = r0 + rr;
            const int slot = ((row % INR) + INR) % INR;
            if constexpr (MODE == 1) {
                // f32 input, single channel -> hi/lo f16 in ch0/1, rest zero
                const float* xin = (const float*)in;
                const int iy = row - 1;                      // padded -> image row
                const bool vr = (iy >= 0) && (iy < H);
                const float* xr = xin + (size_t)img * H * W + (size_t)(vr ? iy : 0) * W;
                f16* ld = inring + slot * FRSPC;
#pragma unroll
                for (int k = 0; k < 2; ++k) {
                    if (k == 1 && lane >= 16) continue;
                    const int ci = 64 * k + lane;            // ring col 0..79
                    const int px = x0 - 8 + ci;
                    const float v = (vr && px >= 0 && px < W) ? xr[px] : 0.f;
                    const f16 h = (f16)v;
                    f16x8 o = {};
                    o[0] = h; o[1] = (f16)(v - (float)h);
                    *(f16x8*)&ld[(size_t)ci * CH] = o;
                }
            } else {
                const int rowc = min(max(row, 0), 513);
                const char* gs = src + (size_t)rowc * ROWBYTES;
                char* ld = (char*)inring + slot * FROWB;
                gload_lds16(gs + lane * 16, ld);                                // 1024 B
                if (lane < 16) gload_lds16(gs + 1024 + lane * 16, ld + 1024);   // 256 B
            }
        }
    };

    const int n = lane & 15, q = lane >> 4;
    int tyv[3], txv[3];
#pragma unroll
    for (int g = 0; g < 3; ++g) { const int t = g * 4 + q; tyv[g] = t / 3 - 1; txv[g] = t % 3 - 1; }
    const int rowoff = q >> 1, choff = (q & 1) * 4;
    const bool xe0 = (xt == 0), xe7 = (xt == 7);

    // A-phase: rows (rA, rA+1); A cols c=16s+n (s=0..4), px = x0-8+c -> aring
    auto computeA = [&](int rA) {
        __builtin_amdgcn_s_setprio(1);
        int irow[3];
#pragma unroll
        for (int g = 0; g < 3; ++g) {
            const int r = rA + tyv[g];
            irow[g] = (((r % INR) + INR) % INR) * FRSPC;
        }
        const int gyA = rA + rowoff;
        const int wrow = (gyA % ARR) * FRSPC;
        const bool zr = (gyA == 0) || (gyA == 513);
#pragma unroll
        for (int s = 0; s < 5; ++s) {
            v4f acc = {0.f,0.f,0.f,0.f}, acc2 = {0.f,0.f,0.f,0.f};
#pragma unroll
            for (int g = 0; g < 3; ++g) {
                const f16x8 xv = *(const f16x8*)&inring[irow[g] + (16 * s + n + txv[g]) * CH];
                acc  = __builtin_amdgcn_mfma_f32_16x16x32_f16(ahiW[g], xv, acc,  0, 0, 0);
                acc2 = __builtin_amdgcn_mfma_f32_16x16x32_f16(aloW[g], xv, acc2, 0, 0, 0);
            }
            const v4f res = acc + acc2;
            f16x4 hv;
#pragma unroll
            for (int c = 0; c < 4; ++c) hv[c] = (f16)fmaxf(res[c], 0.f);
            // SAME-pad for B: zero at global borders (rows 0/513; px -1 at
            // xt==0 -> col 7 (s0,n7); px 512 at xt==7 -> col 72 (s4,n8))
            if (zr || (xe0 && s == 0 && n == 7) || (xe7 && s == 4 && n == 8)) {
                hv[0] = (f16)0.f; hv[1] = (f16)0.f; hv[2] = (f16)0.f; hv[3] = (f16)0.f;
            }
            *(f16x4*)&aring[wrow + (16 * s + n) * CH + choff] = hv;
        }
        __builtin_amdgcn_s_setprio(0);
    };

    // B-phase: rows (rB, rB+1); B px = x0+16s+n (s=0..3)
    auto computeB = [&](int rB) {
        __builtin_amdgcn_s_setprio(1);
        int brow[3];
#pragma unroll
        for (int g = 0; g < 3; ++g) brow[g] = ((rB + tyv[g]) % ARR) * FRSPC;
        const int gyB = rB + rowoff;
        f16* orow = outp + ((size_t)img * ROWS + gyB) * COLS * CH + (size_t)(x0 + 8) * CH + choff;
#pragma unroll
        for (int s = 0; s < 4; ++s) {
            v4f acc = {0.f,0.f,0.f,0.f}, acc2 = {0.f,0.f,0.f,0.f};
#pragma unroll
            for (int g = 0; g < 3; ++g) {
                const f16x8 xv = *(const f16x8*)&aring[brow[g] + (16 * s + n + txv[g] + 8) * CH];
                acc  = __builtin_amdgcn_mfma_f32_16x16x32_f16(bhiW[g], xv, acc,  0, 0, 0);
                acc2 = __builtin_amdgcn_mfma_f32_16x16x32_f16(bloW[g], xv, acc2, 0, 0, 0);
            }
            const v4f res = acc + acc2;
            if constexpr (MODE == 2) {
                // conv20: 8->1, no relu, f32 store (ch0 lives in choff==0 lanes)
                if (choff == 0)
                    outf[((size_t)img * H + (gyB - 1)) * W + (x0 + 16 * s + n)] = res[0];
            } else {
                f16x4 hv;
#pragma unroll
                for (int c = 0; c < 4; ++c) hv[c] = (f16)fmaxf(res[c], 0.f);
                *(f16x4*)(orow + (size_t)(16 * s + n) * CH) = hv;
            }
        }
        __builtin_amdgcn_s_setprio(0);
    };

    // ---- prime: input rows base-1..base+10 (12); A pair (base, base+1) ----
    stage(base - 1, 12);
    __syncthreads();
    if (wave == 0) computeA(base);

    for (int t = 0; t < 4; ++t) {
        computeA(base + 8 * t + 2 + 2 * wave);       // A rows [b+8t+2 .. +9]
        __syncthreads();                             // A visible
        if (t < 3) stage(base + 8 * t + 11, 8);      // rows +11..+18 (for A t+1)
        computeB(base + 8 * t + 1 + 2 * wave);       // B rows [b+8t+1 .. +8]
        __syncthreads();                             // drains staging + stores
    }
}

extern "C" void kernel_launch(void* const* d_in, const int* in_sizes, int n_in,
                              void* d_out, int out_size, void* d_ws, size_t ws_size,
                              hipStream_t stream) {
    const float* x    = (const float*)d_in[0];
    const float* w1   = (const float*)d_in[1];
    const float* wmid = (const float*)d_in[2];
    const float* w20  = (const float*)d_in[3];
    float* out = (float*)d_out;

    const size_t wtab_bytes = (size_t)20 * WTAB_L * 2;
    int g = NB;
    while (g > 1 && 2 * (size_t)g * PLANE_BYTES + wtab_bytes > ws_size) g >>= 1;

    f16* act0 = (f16*)d_ws;
    f16* act1 = act0 + (size_t)g * PLANE_ELEMS;
    f16* wtab = act1 + (size_t)g * PLANE_ELEMS;

    init_kernel<<<dim3(42, g, 2), 256, 0, stream>>>(
        w1, wmid, w20, wtab, act0, (size_t)g * PLANE_ELEMS);

    for (int b0 = 0; b0 < NB; b0 += g) {
        // layers 1+2: f32 input -> act0   (A = wtab slot 19 = conv1, B = slot 0)
        conv2fused<1><<<dim3(g, 8, 16), 256, 0, stream>>>(
            (const f16*)(x + (size_t)b0 * H * W),
            wtab + (size_t)19 * WTAB_L, wtab + (size_t)0 * WTAB_L,
            act0, nullptr);
        // layers (2k+1, 2k+2) for k=1..8: slots (2k-1, 2k); ping-pong planes
        for (int k = 1; k <= 8; ++k) {
            const f16* s0 = (k & 1) ? act0 : act1;
            f16*       d0 = (k & 1) ? act1 : act0;
            conv2fused<0><<<dim3(g, 8, 16), 256, 0, stream>>>(
                s0, wtab + (size_t)(2 * k - 1) * WTAB_L, wtab + (size_t)(2 * k) * WTAB_L,
                d0, nullptr);
        }
        // layers 19+20: act0 -> f32 out  (A = slot 17, B = slot 18 = conv20)
        conv2fused<2><<<dim3(g, 8, 16), 256, 0, stream>>>(
            act0, wtab + (size_t)17 * WTAB_L, wtab + (size_t)18 * WTAB_L,
            nullptr, out + (size_t)b0 * H * W);
    }
}